// Round 6
// baseline (222.734 us; speedup 1.0000x reference)
//
#include <hip/hip_runtime.h>
#include <hip/hip_bf16.h>
#include <math.h>

#define TSEQ 4096
#define CDIM 768
#define NH 12
#define HD 64

typedef float f32x4 __attribute__((ext_vector_type(4)));
typedef __bf16 bf16x8 __attribute__((ext_vector_type(8)));
typedef short s16x8 __attribute__((ext_vector_type(8)));
typedef uint u32x4 __attribute__((ext_vector_type(4)));

__device__ inline ushort f2bf(float f) {
  __hip_bfloat16 h = __float2bfloat16(f);
  return __builtin_bit_cast(ushort, h);
}

__device__ inline void async16(const void* g, void* l) {
  __builtin_amdgcn_global_load_lds(
      (__attribute__((address_space(1))) unsigned int*)(uintptr_t)g,
      (__attribute__((address_space(3))) unsigned int*)(uintptr_t)l, 16, 0, 0);
}

__device__ inline void barrier_all() {
  asm volatile("s_waitcnt vmcnt(0) lgkmcnt(0)" ::: "memory");
  __builtin_amdgcn_sched_barrier(0);
  __builtin_amdgcn_s_barrier();
  __builtin_amdgcn_sched_barrier(0);
}

// v_exp_f32 computes 2^x; s_nop covers the TRANS->VALU hazard
__device__ inline float exp2_fast(float x) {
  float r;
  asm volatile("v_exp_f32 %0, %1\n\ts_nop 0" : "=v"(r) : "v"(x));
  return r;
}

// pack two f32 -> two bf16 in one u32 (lo = a, hi = b)
__device__ inline uint cvtpk(float a, float b) {
  uint r;
  asm volatile("v_cvt_pk_bf16_f32 %0, %1, %2" : "=v"(r) : "v"(a), "v"(b));
  return r;
}

// swizzled fragment read from a [64][64] bf16 tile with row-chunk XOR swizzle
__device__ inline bf16x8 frag_read(const ushort* base, int row, int kk, int lane) {
  const int byte = row * 128 + ((((kk * 4 + (lane >> 4)) ^ (row & 7))) << 4);
  return *(const bf16x8*)((const char*)base + byte);
}

// ---------------- weight transpose fp32 -> bf16, Wt[n][k] = W[k][n] -------
__global__ __launch_bounds__(256) void wconv_t(
    const float* __restrict__ W, ushort* __restrict__ Wt, int K, int N)
{
  __shared__ float sm[32][33];
  const int n0 = blockIdx.x * 32, k0 = blockIdx.y * 32;
  const int c = threadIdx.x & 31, r0 = threadIdx.x >> 5;
#pragma unroll
  for (int i = 0; i < 4; ++i) {
    const int r = r0 + i * 8;
    sm[r][c] = W[(size_t)(k0 + r) * N + n0 + c];
  }
  __syncthreads();
#pragma unroll
  for (int i = 0; i < 4; ++i) {
    const int r = r0 + i * 8;
    Wt[(size_t)(n0 + r) * K + k0 + c] = f2bf(sm[c][r]);
  }
}

// ---------------- layernorm fp32 -> bf16 ---------------------------------
__global__ __launch_bounds__(256) void ln_kernel(
    const float* __restrict__ x, const float* __restrict__ w,
    const float* __restrict__ b, ushort* __restrict__ out)
{
  const int row = blockIdx.x;
  const int tid = threadIdx.x;
  const float* xr = x + (size_t)row * CDIM;
  float v[3];
  float s1 = 0.f, s2 = 0.f;
#pragma unroll
  for (int i = 0; i < 3; ++i) {
    v[i] = xr[tid + i * 256];
    s1 += v[i];
    s2 += v[i] * v[i];
  }
#pragma unroll
  for (int off = 32; off >= 1; off >>= 1) {
    s1 += __shfl_xor(s1, off, 64);
    s2 += __shfl_xor(s2, off, 64);
  }
  __shared__ float red1[4], red2[4];
  if ((tid & 63) == 0) { red1[tid >> 6] = s1; red2[tid >> 6] = s2; }
  __syncthreads();
  s1 = red1[0] + red1[1] + red1[2] + red1[3];
  s2 = red2[0] + red2[1] + red2[2] + red2[3];
  const float mu = s1 * (1.f / CDIM);
  const float var = s2 * (1.f / CDIM) - mu * mu;
  const float inv = rsqrtf(var + 1e-5f);
#pragma unroll
  for (int i = 0; i < 3; ++i) {
    const int c = tid + i * 256;
    out[(size_t)row * CDIM + c] = f2bf((v[i] - mu) * inv * w[c] + b[c]);
  }
}

// ---------------- 128xBN bf16 MFMA GEMM, 2-phase dbuf, C = A@Bt^T + bias --
template <int EPI, int BN>
__global__ __launch_bounds__(256) void gemm_bt(
    const ushort* __restrict__ A, const ushort* __restrict__ Bt,
    const float* __restrict__ bias, const float* __restrict__ res,
    ushort* __restrict__ outb, float* __restrict__ outf,
    int M, int N, int K, int gx)
{
  constexpr int NW = BN / 32;
  __shared__ __align__(16) ushort As[2][128 * 32];
  __shared__ __align__(16) ushort Bs[2][BN * 32];
  const int tid = threadIdx.x;
  const int lane = tid & 63;
  const int wv = tid >> 6;
  const int nwg = (int)gridDim.x;
  const int bid = (int)blockIdx.x;
  const int sw = (bid & 7) * (nwg >> 3) + (bid >> 3);
  const int rowBase = (sw / gx) * 128;
  const int colBase = (sw % gx) * BN;
  const int wr = (wv >> 1) * 64;
  const int wc = (wv & 1) * (BN / 2);

  f32x4 acc[4][NW] = {};

  const int e0 = tid * 8;
  const int r0 = e0 >> 5, c0 = e0 & 31;
  const int e1 = (tid + 256) * 8;
  const int r1 = e1 >> 5, c1 = e1 & 31;

  const ushort* Ag0 = A + (size_t)(rowBase + r0) * K + c0;
  const ushort* Ag1 = A + (size_t)(rowBase + r1) * K + c1;
  const ushort* Bg0 = Bt + (size_t)(colBase + r0) * K + c0;
  const ushort* Bg1 = Bt + (size_t)(colBase + r1) * K + c1;

  auto stage = [&](int buf, int k0) {
    async16(Ag0 + k0, &As[buf][e0]);
    async16(Ag1 + k0, &As[buf][e1]);
    async16(Bg0 + k0, &Bs[buf][e0]);
    if (BN == 128) async16(Bg1 + k0, &Bs[buf][e1]);
  };

  stage(0, 0);
  int buf = 0;
  for (int k0 = 0; k0 < K; k0 += 32) {
    barrier_all();
    if (k0 + 32 < K) stage(buf ^ 1, k0 + 32);
    bf16x8 af[4], bfr[NW];
#pragma unroll
    for (int m = 0; m < 4; ++m)
      af[m] = *(const bf16x8*)&As[buf][(wr + m * 16 + (lane & 15)) * 32 + (lane >> 4) * 8];
#pragma unroll
    for (int n = 0; n < NW; ++n)
      bfr[n] = *(const bf16x8*)&Bs[buf][(wc + n * 16 + (lane & 15)) * 32 + (lane >> 4) * 8];
#pragma unroll
    for (int m = 0; m < 4; ++m)
#pragma unroll
      for (int n = 0; n < NW; ++n)
        acc[m][n] = __builtin_amdgcn_mfma_f32_16x16x32_bf16(af[m], bfr[n], acc[m][n], 0, 0, 0);
    buf ^= 1;
  }

#pragma unroll
  for (int n = 0; n < NW; ++n) {
    const int gc = colBase + wc + n * 16 + (lane & 15);
    const float bv = bias[gc];
#pragma unroll
    for (int m = 0; m < 4; ++m) {
#pragma unroll
      for (int j = 0; j < 4; ++j) {
        const int gr = rowBase + wr + m * 16 + (lane >> 4) * 4 + j;
        const float v = acc[m][n][j] + bv;
        if (EPI == 0) {
          outb[(size_t)gr * N + gc] = f2bf(v);
        } else if (EPI == 1) {
          outf[(size_t)gr * N + gc] = res[(size_t)gr * N + gc] + v;
        } else {
          const float g = 0.5f * v * (1.0f + erff(v * 0.70710678118654752f));
          outb[(size_t)gr * N + gc] = f2bf(g);
        }
      }
    }
  }
}

// ---------------- causal flash attention: wave-owns-kv-tile --------------
// Wave wv handles kv-tiles kb ≡ wv (mod 4) for all 64 q rows of its block.
// Fixed-max softmax => partials are additive; one LDS merge at the end.
// No main-loop barriers (all LDS wave-private). K: gload_lds + XOR swizzle
// (round-4-verified). V^T: reg-stage + sigma pack-write (round-4-verified).
__global__ __launch_bounds__(256, 1) void attn_kernel(
    const ushort* __restrict__ qkv, ushort* __restrict__ att)
{
  __shared__ __align__(16) char smem[98304];  // per wave: K[2][8K] + Vt[8K]
  const int tid = threadIdx.x;
  const int lane = tid & 63;
  const int wv = tid >> 6;
  const int g = (lane >> 4) & 3;
  const int ql = lane & 15;
  // snake remap: CU's resident blocks {p, 511-p, 512+p} -> balanced work
  const int p_ = blockIdx.x & 255, grp = blockIdx.x >> 8;
  const int item = (grp & 1) ? (grp * 256 + 255 - p_) : (grp * 256 + p_);
  const int qb = 63 - item / 12;
  const int h = item % 12;
  const int t0 = qb * 64;
  const int rs = 3 * CDIM;
  const int qo = h * HD, ko = CDIM + h * HD, vo = 2 * CDIM + h * HD;

  const float cexp = 0.18033688f;             // 0.125 * log2(e)
  const float cbias = -32.0f * 0.18033688f;   // fixed max M_raw = 32

  char* wbase = smem + wv * 24576;
  char* vtile = wbase + 16384;

  // Q fragments (B-operand): row t0+16qg+ql, d = kk*32 + g*8 .. +8
  bf16x8 qf[4][2];
#pragma unroll
  for (int qg = 0; qg < 4; ++qg) {
    const ushort* qrow = qkv + (size_t)(t0 + 16 * qg + ql) * rs + qo + g * 8;
    qf[qg][0] = *(const bf16x8*)(qrow);
    qf[qg][1] = *(const bf16x8*)(qrow + 32);
  }

  // K staging: LDS row i*8+krow chunk lane&7 <- source chunk (lane&7)^krow
  const int krow = lane >> 3;
  const ushort* bKsrc = qkv + (size_t)(wv * 64 + krow) * rs + ko + ((lane & 7) ^ krow) * 8;

  // V: lane covers keys {16i+vt2, 16i+vt2+1} x d in [vd, vd+8), i=0..3
  const int vt2 = (lane >> 3) * 2;
  const int vd = (lane & 7) * 8;
  const ushort* bVsrc = qkv + (size_t)(wv * 64 + vt2) * rs + vo + vd;
  // sigma(key)=32*(n>>1)+8*(key>>2&3)+4*(n&1)+(key&3), n=key>>4; byte=2*sigma
  int slot2[4];
#pragma unroll
  for (int i = 0; i < 4; ++i)
    slot2[i] = (32 * (i >> 1) + 8 * (vt2 >> 2) + 4 * (i & 1) + (vt2 & 3)) * 2;

  const int nt = (qb >= wv) ? ((qb - wv) >> 2) + 1 : 0;

  auto stageK = [&](int buf, size_t koff) {
    char* dK = wbase + buf * 8192;
#pragma unroll
    for (int i = 0; i < 8; ++i)
      async16(bKsrc + koff + (size_t)i * 8 * rs, dK + i * 1024 + lane * 16);
  };

  s16x8 vr[4][2];
  if (nt > 0) {
    stageK(0, 0);
#pragma unroll
    for (int i = 0; i < 4; ++i) {
      vr[i][0] = *(const s16x8*)(bVsrc + (size_t)i * 16 * rs);
      vr[i][1] = *(const s16x8*)(bVsrc + (size_t)i * 16 * rs + rs);
    }
  }

  f32x4 accO[4][4] = {};
  f32x4 accL[4] = {};
  const bf16x8 ones = __builtin_bit_cast(bf16x8,
      (u32x4){0x3F803F80u, 0x3F803F80u, 0x3F803F80u, 0x3F803F80u});

  int kv0 = wv * 64;
  int cur = 0;
  for (int it = 0; it < nt; ++it) {
    asm volatile("s_waitcnt vmcnt(0)" ::: "memory");   // K(it) LDS, V(it) regs
    __builtin_amdgcn_sched_barrier(0);
    const size_t nextoff = (size_t)(it + 1) * 256 * rs;
    const bool pre = (it + 1 < nt);
    if (pre) stageK(cur ^ 1, nextoff);

    // pack-write V^T(it); prior PV reads of vtile are older DS ops (in-order)
#pragma unroll
    for (int i = 0; i < 4; ++i) {
#pragma unroll
      for (int jj = 0; jj < 8; ++jj) {
        const int d = vd + jj;
        const uint val = (uint)(ushort)vr[i][0][jj] | ((uint)(ushort)vr[i][1][jj] << 16);
        *(uint*)(vtile + d * 128 + (slot2[i] ^ (((d >> 1) & 7) << 4))) = val;
      }
    }
    if (pre) {   // reload vr for next tile (issues after pack-write reads)
#pragma unroll
      for (int i = 0; i < 4; ++i) {
        vr[i][0] = *(const s16x8*)(bVsrc + nextoff + (size_t)i * 16 * rs);
        vr[i][1] = *(const s16x8*)(bVsrc + nextoff + (size_t)i * 16 * rs + rs);
      }
    }

    // QK^T: A = K rows, B = Q; D[key 16kg+4g+j][q 16qg+ql]
    const ushort* Kt = (const ushort*)(wbase + cur * 8192);
    const bool diag = (kv0 == t0);
    uint paw[4][8];
#pragma unroll
    for (int kg = 0; kg < 4; ++kg) {
      const bf16x8 A0 = frag_read(Kt, kg * 16 + ql, 0, lane);
      const bf16x8 A1 = frag_read(Kt, kg * 16 + ql, 1, lane);
      f32x4 s[4];
#pragma unroll
      for (int qg = 0; qg < 4; ++qg) {
        s[qg] = __builtin_amdgcn_mfma_f32_16x16x32_bf16(A0, qf[qg][0], (f32x4){0.f, 0.f, 0.f, 0.f}, 0, 0, 0);
        s[qg] = __builtin_amdgcn_mfma_f32_16x16x32_bf16(A1, qf[qg][1], s[qg], 0, 0, 0);
      }
#pragma unroll
      for (int qg = 0; qg < 4; ++qg) {
        float e[4];
#pragma unroll
        for (int j = 0; j < 4; ++j) {
          float p = exp2_fast(fmaf(s[qg][j], cexp, cbias));
          if (diag && (kv0 + kg * 16 + 4 * g + j) > (t0 + 16 * qg + ql)) p = 0.f;
          e[j] = p;
        }
        paw[qg][(kg >> 1) * 4 + (kg & 1) * 2]     = cvtpk(e[0], e[1]);
        paw[qg][(kg >> 1) * 4 + (kg & 1) * 2 + 1] = cvtpk(e[2], e[3]);
      }
    }
    bf16x8 pa[4][2];
#pragma unroll
    for (int qg = 0; qg < 4; ++qg) {
      pa[qg][0] = __builtin_bit_cast(bf16x8, (u32x4){paw[qg][0], paw[qg][1], paw[qg][2], paw[qg][3]});
      pa[qg][1] = __builtin_bit_cast(bf16x8, (u32x4){paw[qg][4], paw[qg][5], paw[qg][6], paw[qg][7]});
    }

    asm volatile("s_waitcnt lgkmcnt(0)" ::: "memory");  // V^T writes landed
    __builtin_amdgcn_sched_barrier(0);

    // PV: B = Vt rows (d), k-dim = sigma slots; D[q 4g+j][d 16dg+ql]
#pragma unroll
    for (int dg = 0; dg < 4; ++dg) {
#pragma unroll
      for (int kk = 0; kk < 2; ++kk) {
        const int byte = (16 * dg + ql) * 128 + ((kk * 64 + g * 16) ^ (((ql >> 1) & 7) << 4));
        const bf16x8 bv = *(const bf16x8*)(vtile + byte);
#pragma unroll
        for (int qg = 0; qg < 4; ++qg)
          accO[qg][dg] = __builtin_amdgcn_mfma_f32_16x16x32_bf16(pa[qg][kk], bv, accO[qg][dg], 0, 0, 0);
      }
    }
#pragma unroll
    for (int qg = 0; qg < 4; ++qg) {
      accL[qg] = __builtin_amdgcn_mfma_f32_16x16x32_bf16(pa[qg][0], ones, accL[qg], 0, 0, 0);
      accL[qg] = __builtin_amdgcn_mfma_f32_16x16x32_bf16(pa[qg][1], ones, accL[qg], 0, 0, 0);
    }
    kv0 += 256;
    cur ^= 1;
  }

  // -------- merge the 4 wave partials (fixed-max => exactly additive) ----
  __syncthreads();
  float* smO = (float*)smem;                    // [w*64+d][q^swz] 64KB
  float* smL = (float*)(smem + 65536);          // [w*64+q] 1KB
#pragma unroll
  for (int qg = 0; qg < 4; ++qg)
#pragma unroll
    for (int dg = 0; dg < 4; ++dg) {
      const int d = 16 * dg + ql;
      *(f32x4*)&smO[(size_t)(wv * 64 + d) * 64 + ((16 * qg + 4 * g) ^ ((d & 7) << 2))] = accO[qg][dg];
    }
  if (ql == 0) {
#pragma unroll
    for (int qg = 0; qg < 4; ++qg)
      *(f32x4*)&smL[wv * 64 + 16 * qg + 4 * g] = accL[qg];
  }
  __syncthreads();

  const int q0 = 16 * wv + 4 * g;               // wave outputs q rows [16wv,16wv+16)
  f32x4 ls = {0.f, 0.f, 0.f, 0.f};
#pragma unroll
  for (int w2 = 0; w2 < 4; ++w2) ls += *(const f32x4*)&smL[w2 * 64 + q0];
  f32x4 inv;
#pragma unroll
  for (int j = 0; j < 4; ++j) inv[j] = 1.0f / ls[j];
#pragma unroll
  for (int n = 0; n < 4; ++n) {
    const int d = 16 * n + ql;
    f32x4 o = {0.f, 0.f, 0.f, 0.f};
#pragma unroll
    for (int w2 = 0; w2 < 4; ++w2)
      o += *(const f32x4*)&smO[(size_t)(w2 * 64 + d) * 64 + (q0 ^ ((d & 7) << 2))];
#pragma unroll
    for (int j = 0; j < 4; ++j)
      att[(size_t)(t0 + q0 + j) * CDIM + h * HD + d] = f2bf(o[j] * inv[j]);
  }
}

// -------------------------------------------------------------------------
extern "C" void kernel_launch(void* const* d_in, const int* in_sizes, int n_in,
                              void* d_out, int out_size, void* d_ws, size_t ws_size,
                              hipStream_t stream)
{
  const float* x      = (const float*)d_in[0];
  const float* ln1_w  = (const float*)d_in[1];
  const float* ln1_b  = (const float*)d_in[2];
  const float* W_attn = (const float*)d_in[3];
  const float* b_attn = (const float*)d_in[4];
  const float* W_proj = (const float*)d_in[5];
  const float* b_proj = (const float*)d_in[6];
  const float* ln2_w  = (const float*)d_in[7];
  const float* ln2_b  = (const float*)d_in[8];
  const float* W_fc   = (const float*)d_in[9];
  const float* b_fc   = (const float*)d_in[10];
  const float* W_fc2  = (const float*)d_in[11];
  const float* b_fc2  = (const float*)d_in[12];
  float* out = (float*)d_out;

  char* base = (char*)d_ws;
  size_t off = 0;
  auto alloc = [&](size_t bytes) -> void* {
    void* q = base + off;
    off = (off + bytes + 255) & ~(size_t)255;
    return q;
  };
  ushort* Wt_attn = (ushort*)alloc(768ull * 2304 * 2);
  ushort* Wt_proj = (ushort*)alloc(768ull * 768 * 2);
  ushort* Wt_fc   = (ushort*)alloc(768ull * 3072 * 2);
  ushort* Wt_fc2  = (ushort*)alloc(3072ull * 768 * 2);
  ushort* t_ln    = (ushort*)alloc(4096ull * 768 * 2);
  ushort* t_att   = (ushort*)alloc(4096ull * 768 * 2);
  float*  t_x1    = (float*) alloc(4096ull * 768 * 4);
  ushort* t_big   = (ushort*)alloc(4096ull * 3072 * 2);
  ushort* t_qkv = t_big;
  ushort* t_h   = t_big;

  wconv_t<<<dim3(2304 / 32, 768 / 32), 256, 0, stream>>>(W_attn, Wt_attn, 768, 2304);
  wconv_t<<<dim3(768 / 32, 768 / 32), 256, 0, stream>>>(W_proj, Wt_proj, 768, 768);
  wconv_t<<<dim3(3072 / 32, 768 / 32), 256, 0, stream>>>(W_fc, Wt_fc, 768, 3072);
  wconv_t<<<dim3(768 / 32, 3072 / 32), 256, 0, stream>>>(W_fc2, Wt_fc2, 3072, 768);

  ln_kernel<<<4096, 256, 0, stream>>>(x, ln1_w, ln1_b, t_ln);
  gemm_bt<0, 128><<<18 * 32, 256, 0, stream>>>(
      t_ln, Wt_attn, b_attn, nullptr, t_qkv, nullptr, 4096, 2304, 768, 18);
  attn_kernel<<<dim3(768), 256, 0, stream>>>(t_qkv, t_att);
  gemm_bt<1, 64><<<12 * 32, 256, 0, stream>>>(
      t_att, Wt_proj, b_proj, x, nullptr, t_x1, 4096, 768, 768, 12);
  ln_kernel<<<4096, 256, 0, stream>>>(t_x1, ln2_w, ln2_b, t_ln);
  gemm_bt<2, 128><<<24 * 32, 256, 0, stream>>>(
      t_ln, Wt_fc, b_fc, nullptr, t_h, nullptr, 4096, 3072, 768, 24);
  gemm_bt<1, 64><<<12 * 32, 256, 0, stream>>>(
      t_h, Wt_fc2, b_fc2, t_x1, nullptr, out, 4096, 768, 3072, 12);
}

// Round 7
// 205.073 us; speedup vs baseline: 1.0861x; 1.0861x over previous
//
#include <hip/hip_runtime.h>
#include <hip/hip_bf16.h>
#include <math.h>

#define TSEQ 4096
#define CDIM 768
#define NH 12
#define HD 64

typedef float f32x4 __attribute__((ext_vector_type(4)));
typedef __bf16 bf16x8 __attribute__((ext_vector_type(8)));
typedef short s16x8 __attribute__((ext_vector_type(8)));
typedef uint u32x4 __attribute__((ext_vector_type(4)));

__device__ inline ushort f2bf(float f) {
  __hip_bfloat16 h = __float2bfloat16(f);
  return __builtin_bit_cast(ushort, h);
}

__device__ inline void async16(const void* g, void* l) {
  __builtin_amdgcn_global_load_lds(
      (__attribute__((address_space(1))) unsigned int*)(uintptr_t)g,
      (__attribute__((address_space(3))) unsigned int*)(uintptr_t)l, 16, 0, 0);
}

// v_exp_f32 computes 2^x; s_nop covers the TRANS->VALU hazard
__device__ inline float exp2_fast(float x) {
  float r;
  asm volatile("v_exp_f32 %0, %1\n\ts_nop 0" : "=v"(r) : "v"(x));
  return r;
}

// pack two f32 -> two bf16 in one u32 (lo = a, hi = b)
__device__ inline uint cvtpk(float a, float b) {
  uint r;
  asm volatile("v_cvt_pk_bf16_f32 %0, %1, %2" : "=v"(r) : "v"(a), "v"(b));
  return r;
}

// swizzled fragment read from a [64][64] bf16 tile with row-chunk XOR swizzle
__device__ inline bf16x8 frag_read(const ushort* base, int row, int kk, int lane) {
  const int byte = row * 128 + ((((kk * 4 + (lane >> 4)) ^ (row & 7))) << 4);
  return *(const bf16x8*)((const char*)base + byte);
}

// ---------------- weight transpose fp32 -> bf16, Wt[n][k] = W[k][n] -------
__global__ __launch_bounds__(256) void wconv_t(
    const float* __restrict__ W, ushort* __restrict__ Wt, int K, int N)
{
  __shared__ float sm[32][33];
  const int n0 = blockIdx.x * 32, k0 = blockIdx.y * 32;
  const int c = threadIdx.x & 31, r0 = threadIdx.x >> 5;
#pragma unroll
  for (int i = 0; i < 4; ++i) {
    const int r = r0 + i * 8;
    sm[r][c] = W[(size_t)(k0 + r) * N + n0 + c];
  }
  __syncthreads();
#pragma unroll
  for (int i = 0; i < 4; ++i) {
    const int r = r0 + i * 8;
    Wt[(size_t)(n0 + r) * K + k0 + c] = f2bf(sm[c][r]);
  }
}

// ---------------- layernorm fp32 -> bf16 ---------------------------------
__global__ __launch_bounds__(256) void ln_kernel(
    const float* __restrict__ x, const float* __restrict__ w,
    const float* __restrict__ b, ushort* __restrict__ out)
{
  const int row = blockIdx.x;
  const int tid = threadIdx.x;
  const float* xr = x + (size_t)row * CDIM;
  float v[3];
  float s1 = 0.f, s2 = 0.f;
#pragma unroll
  for (int i = 0; i < 3; ++i) {
    v[i] = xr[tid + i * 256];
    s1 += v[i];
    s2 += v[i] * v[i];
  }
#pragma unroll
  for (int off = 32; off >= 1; off >>= 1) {
    s1 += __shfl_xor(s1, off, 64);
    s2 += __shfl_xor(s2, off, 64);
  }
  __shared__ float red1[4], red2[4];
  if ((tid & 63) == 0) { red1[tid >> 6] = s1; red2[tid >> 6] = s2; }
  __syncthreads();
  s1 = red1[0] + red1[1] + red1[2] + red1[3];
  s2 = red2[0] + red2[1] + red2[2] + red2[3];
  const float mu = s1 * (1.f / CDIM);
  const float var = s2 * (1.f / CDIM) - mu * mu;
  const float inv = rsqrtf(var + 1e-5f);
#pragma unroll
  for (int i = 0; i < 3; ++i) {
    const int c = tid + i * 256;
    out[(size_t)row * CDIM + c] = f2bf((v[i] - mu) * inv * w[c] + b[c]);
  }
}

// ------- 128xBN bf16 MFMA GEMM, 3-stage pipeline (counted vmcnt) ---------
// EPI 0: bf16 out;  EPI 1: fp32 out = res + v;  EPI 2: bf16 out = gelu(v)
template <int EPI, int BN>
__global__ __launch_bounds__(256) void gemm_bt(
    const ushort* __restrict__ A, const ushort* __restrict__ Bt,
    const float* __restrict__ bias, const float* __restrict__ res,
    ushort* __restrict__ outb, float* __restrict__ outf,
    int M, int N, int K, int gx)
{
  constexpr int NW = BN / 32;
  __shared__ __align__(16) ushort As[3][128 * 32];
  __shared__ __align__(16) ushort Bs[3][BN * 32];
  const int tid = threadIdx.x;
  const int lane = tid & 63;
  const int wv = tid >> 6;
  const int nwg = (int)gridDim.x;
  const int bid = (int)blockIdx.x;
  const int sw = (bid & 7) * (nwg >> 3) + (bid >> 3);
  const int rowBase = (sw / gx) * 128;
  const int colBase = (sw % gx) * BN;
  const int wr = (wv >> 1) * 64;
  const int wc = (wv & 1) * (BN / 2);

  f32x4 acc[4][NW] = {};

  const int e0 = tid * 8;
  const int r0 = e0 >> 5, c0 = e0 & 31;
  const int e1 = (tid + 256) * 8;
  const int r1 = e1 >> 5, c1 = e1 & 31;

  const ushort* Ag0 = A + (size_t)(rowBase + r0) * K + c0;
  const ushort* Ag1 = A + (size_t)(rowBase + r1) * K + c1;
  const ushort* Bg0 = Bt + (size_t)(colBase + r0) * K + c0;
  const ushort* Bg1 = Bt + (size_t)(colBase + r1) * K + c1;

  auto stage = [&](int buf, int k0) {
    async16(Ag0 + k0, &As[buf][e0]);
    async16(Ag1 + k0, &As[buf][e1]);
    async16(Bg0 + k0, &Bs[buf][e0]);
    if (BN == 128) async16(Bg1 + k0, &Bs[buf][e1]);
  };

  const int nt = K / 32;
  stage(0, 0);
  stage(1, 32);
  int b0 = 0, b1 = 1, b2 = 2;
  for (int t = 0; t < nt; ++t) {
    if (t < nt - 1) {
      if (BN == 128) asm volatile("s_waitcnt vmcnt(4)" ::: "memory");
      else           asm volatile("s_waitcnt vmcnt(3)" ::: "memory");
    } else {
      asm volatile("s_waitcnt vmcnt(0)" ::: "memory");
    }
    __builtin_amdgcn_sched_barrier(0);
    __builtin_amdgcn_s_barrier();
    __builtin_amdgcn_sched_barrier(0);
    if (t + 2 < nt) stage(b2, t * 32 + 64);

    bf16x8 af[4], bfr[NW];
#pragma unroll
    for (int m = 0; m < 4; ++m)
      af[m] = *(const bf16x8*)&As[b0][(wr + m * 16 + (lane & 15)) * 32 + (lane >> 4) * 8];
#pragma unroll
    for (int n = 0; n < NW; ++n)
      bfr[n] = *(const bf16x8*)&Bs[b0][(wc + n * 16 + (lane & 15)) * 32 + (lane >> 4) * 8];
    __builtin_amdgcn_s_setprio(1);
#pragma unroll
    for (int m = 0; m < 4; ++m)
#pragma unroll
      for (int n = 0; n < NW; ++n)
        acc[m][n] = __builtin_amdgcn_mfma_f32_16x16x32_bf16(af[m], bfr[n], acc[m][n], 0, 0, 0);
    __builtin_amdgcn_s_setprio(0);
    const int tmp = b0; b0 = b1; b1 = b2; b2 = tmp;
  }

#pragma unroll
  for (int n = 0; n < NW; ++n) {
    const int gc = colBase + wc + n * 16 + (lane & 15);
    const float bv = bias[gc];
#pragma unroll
    for (int m = 0; m < 4; ++m) {
#pragma unroll
      for (int j = 0; j < 4; ++j) {
        const int gr = rowBase + wr + m * 16 + (lane >> 4) * 4 + j;
        const float v = acc[m][n][j] + bv;
        if (EPI == 0) {
          outb[(size_t)gr * N + gc] = f2bf(v);
        } else if (EPI == 1) {
          outf[(size_t)gr * N + gc] = res[(size_t)gr * N + gc] + v;
        } else {
          const float g = 0.5f * v * (1.0f + erff(v * 0.70710678118654752f));
          outb[(size_t)gr * N + gc] = f2bf(g);
        }
      }
    }
  }
}

// ---------------- causal flash attention, 64x64 tiles, hd=64 -------------
// Round-4 structure (swapped QK^T, in-register P, sigma-permuted V^T) with
// counted-vmcnt pipeline: vr(t+1) issued pre-wait, K(t+1) staged post-barrier,
// top wait = vmcnt(2) (K(t) done, vr(t+1) in flight).
__global__ __launch_bounds__(256) void attn_kernel(
    const ushort* __restrict__ qkv, ushort* __restrict__ att)
{
  __shared__ __align__(16) ushort Ks[2][64 * 64];
  __shared__ __align__(16) ushort Vt[2][64 * 64];   // V^T [d][sigma(key)]

  const int tid = threadIdx.x;
  const int lane = tid & 63;
  const int wv = tid >> 6;
  const int g = lane >> 4;
  const int ql = lane & 15;
  // snake remap: CU's resident blocks {p, 511-p, 512+p} -> balanced work
  const int p_ = blockIdx.x & 255, grp = blockIdx.x >> 8;
  const int item = (grp & 1) ? (grp * 256 + 255 - p_) : (grp * 256 + p_);
  const int qb = 63 - (item / 12);
  const int h = item % 12;
  const int t0 = qb * 64;
  const size_t rs = 3 * CDIM;
  const int qo = h * HD, ko = CDIM + h * HD, vo = 2 * CDIM + h * HD;

  const float cexp = 0.18033688f;            // 0.125 * log2(e)
  const float cbias = -32.0f * 0.18033688f;  // fixed max M_raw = 32

  // K staging: pre-swizzled global source -> linear LDS dest
  const int L0 = tid * 16, L1 = (tid + 256) * 16;
  const int r_0 = L0 >> 7, c_0 = ((L0 >> 4) & 7) ^ (r_0 & 7);
  const int r_1 = L1 >> 7, c_1 = ((L1 >> 4) & 7) ^ (r_1 & 7);
  const ushort* kg0 = qkv + (size_t)r_0 * rs + ko + c_0 * 8;
  const ushort* kg1 = qkv + (size_t)r_1 * rs + ko + c_1 * 8;

  // V reg staging: keys (vt, vt+1) x d in [vd, vd+8); sigma-permuted slot
  const int vt = (tid >> 3) * 2;
  const int vd = (tid & 7) * 8;
  const int slot2 = (32 * ((vt >> 4) >> 1) + 8 * ((vt >> 2) & 3) +
                     4 * ((vt >> 4) & 1) + (vt & 3)) * 2;  // byte offset in row
  const ushort* vg = qkv + (size_t)vt * rs + vo + vd;

  // Q fragments direct from global (bf16, 16B aligned)
  const ushort* qrow = qkv + (size_t)(t0 + wv * 16 + ql) * rs + qo + g * 8;
  const bf16x8 aq0 = *(const bf16x8*)(qrow);
  const bf16x8 aq1 = *(const bf16x8*)(qrow + 32);

  // prologue: vr(0), K(0) -> LDS, pack-write V^T(0)
  s16x8 vA0 = *(const s16x8*)(vg);
  s16x8 vA1 = *(const s16x8*)(vg + rs);
  async16(kg0, (char*)Ks[0] + L0);
  async16(kg1, (char*)Ks[0] + L1);
#pragma unroll
  for (int jj = 0; jj < 8; ++jj) {      // compiler waits vr(0) here
    const int d = vd + jj;
    const uint val = (uint)(ushort)vA0[jj] | ((uint)(ushort)vA1[jj] << 16);
    *(uint*)((char*)Vt[0] + d * 128 + (slot2 ^ (((d >> 1) & 7) << 4))) = val;
  }

  float lsum = 0.f;
  f32x4 accO[4] = {};
  const int swzv = (ql >> 1) & 7;

  int cur = 0;
  for (int kb = 0; kb <= qb; ++kb) {
    const bool pre = (kb < qb);
    const bool diag = (kb == qb);
    const size_t koff = (size_t)(kb + 1) * 64 * rs;

    // issue vr(kb+1) before the wait (stays in flight across this body)
    if (pre) {
      vA0 = *(const s16x8*)(vg + koff);
      vA1 = *(const s16x8*)(vg + koff + rs);
    }
    if (pre) asm volatile("s_waitcnt vmcnt(2) lgkmcnt(0)" ::: "memory");
    else     asm volatile("s_waitcnt vmcnt(0) lgkmcnt(0)" ::: "memory");
    __builtin_amdgcn_sched_barrier(0);
    __builtin_amdgcn_s_barrier();
    __builtin_amdgcn_sched_barrier(0);

    // stage K(kb+1) post-barrier (other buffer; readers of it passed barrier)
    if (pre) {
      async16(kg0 + koff, (char*)Ks[cur ^ 1] + L0);
      async16(kg1 + koff, (char*)Ks[cur ^ 1] + L1);
    }

    // QK^T swapped: D[key][q], key = 16n + 4g + j, q = wv*16 + ql
    f32x4 accS[4] = {};
    __builtin_amdgcn_s_setprio(1);
#pragma unroll
    for (int kk = 0; kk < 2; ++kk) {
      const bf16x8 a_q = kk ? aq1 : aq0;
#pragma unroll
      for (int n = 0; n < 4; ++n)
        accS[n] = __builtin_amdgcn_mfma_f32_16x16x32_bf16(
            frag_read(Ks[cur], n * 16 + ql, kk, lane), a_q, accS[n], 0, 0, 0);
    }
    __builtin_amdgcn_s_setprio(0);

    // p = 2^(s*c + cbias), diag mask, row-sum, pack to A-fragments in-reg
    uint pk[8];
#pragma unroll
    for (int n = 0; n < 4; ++n) {
      float pv[4];
#pragma unroll
      for (int j = 0; j < 4; ++j) {
        float s = exp2_fast(fmaf(accS[n][j], cexp, cbias));
        if (diag && (kb * 64 + 16 * n + 4 * g + j) > (t0 + wv * 16 + ql)) s = 0.f;
        pv[j] = s;
        lsum += s;
      }
      pk[2 * n] = cvtpk(pv[0], pv[1]);
      pk[2 * n + 1] = cvtpk(pv[2], pv[3]);
    }
    const bf16x8 pf0 = __builtin_bit_cast(bf16x8, (u32x4){pk[0], pk[1], pk[2], pk[3]});
    const bf16x8 pf1 = __builtin_bit_cast(bf16x8, (u32x4){pk[4], pk[5], pk[6], pk[7]});

    // PV: D[q][d]; A = in-reg P, B = Vt rows (d), k-dim = sigma slots
    __builtin_amdgcn_s_setprio(1);
#pragma unroll
    for (int kk = 0; kk < 2; ++kk) {
      const bf16x8 a_p = kk ? pf1 : pf0;
#pragma unroll
      for (int n = 0; n < 4; ++n) {
        const int byte = (n * 16 + ql) * 128 + ((kk * 64 + g * 16) ^ (swzv << 4));
        const bf16x8 bv = *(const bf16x8*)((const char*)Vt[cur] + byte);
        accO[n] = __builtin_amdgcn_mfma_f32_16x16x32_bf16(a_p, bv, accO[n], 0, 0, 0);
      }
    }
    __builtin_amdgcn_s_setprio(0);

    // pack-write V^T(kb+1) (vr had the whole body to land; visible after
    // next barrier; all waves' reads of this buffer finished pre-barrier)
    if (pre) {
#pragma unroll
      for (int jj = 0; jj < 8; ++jj) {
        const int d = vd + jj;
        const uint val = (uint)(ushort)vA0[jj] | ((uint)(ushort)vA1[jj] << 16);
        *(uint*)((char*)Vt[cur ^ 1] + d * 128 + (slot2 ^ (((d >> 1) & 7) << 4))) = val;
      }
    }
    cur ^= 1;
  }

  // l[q]: sum partial rows over the 4 lane-groups
  lsum += __shfl_xor(lsum, 16, 64);
  lsum += __shfl_xor(lsum, 32, 64);
  float inv[4];
#pragma unroll
  for (int jr = 0; jr < 4; ++jr)
    inv[jr] = 1.0f / __shfl(lsum, 4 * g + jr, 64);
#pragma unroll
  for (int n = 0; n < 4; ++n)
#pragma unroll
    for (int jr = 0; jr < 4; ++jr) {
      const int tq = t0 + wv * 16 + 4 * g + jr;
      const int d = n * 16 + ql;
      att[(size_t)tq * CDIM + h * HD + d] = f2bf(accO[n][jr] * inv[jr]);
    }
}

// -------------------------------------------------------------------------
extern "C" void kernel_launch(void* const* d_in, const int* in_sizes, int n_in,
                              void* d_out, int out_size, void* d_ws, size_t ws_size,
                              hipStream_t stream)
{
  const float* x      = (const float*)d_in[0];
  const float* ln1_w  = (const float*)d_in[1];
  const float* ln1_b  = (const float*)d_in[2];
  const float* W_attn = (const float*)d_in[3];
  const float* b_attn = (const float*)d_in[4];
  const float* W_proj = (const float*)d_in[5];
  const float* b_proj = (const float*)d_in[6];
  const float* ln2_w  = (const float*)d_in[7];
  const float* ln2_b  = (const float*)d_in[8];
  const float* W_fc   = (const float*)d_in[9];
  const float* b_fc   = (const float*)d_in[10];
  const float* W_fc2  = (const float*)d_in[11];
  const float* b_fc2  = (const float*)d_in[12];
  float* out = (float*)d_out;

  char* base = (char*)d_ws;
  size_t off = 0;
  auto alloc = [&](size_t bytes) -> void* {
    void* q = base + off;
    off = (off + bytes + 255) & ~(size_t)255;
    return q;
  };
  ushort* Wt_attn = (ushort*)alloc(768ull * 2304 * 2);
  ushort* Wt_proj = (ushort*)alloc(768ull * 768 * 2);
  ushort* Wt_fc   = (ushort*)alloc(768ull * 3072 * 2);
  ushort* Wt_fc2  = (ushort*)alloc(3072ull * 768 * 2);
  ushort* t_ln    = (ushort*)alloc(4096ull * 768 * 2);
  ushort* t_att   = (ushort*)alloc(4096ull * 768 * 2);
  float*  t_x1    = (float*) alloc(4096ull * 768 * 4);
  ushort* t_big   = (ushort*)alloc(4096ull * 3072 * 2);
  ushort* t_qkv = t_big;
  ushort* t_h   = t_big;

  wconv_t<<<dim3(2304 / 32, 768 / 32), 256, 0, stream>>>(W_attn, Wt_attn, 768, 2304);
  wconv_t<<<dim3(768 / 32, 768 / 32), 256, 0, stream>>>(W_proj, Wt_proj, 768, 768);
  wconv_t<<<dim3(3072 / 32, 768 / 32), 256, 0, stream>>>(W_fc, Wt_fc, 768, 3072);
  wconv_t<<<dim3(768 / 32, 3072 / 32), 256, 0, stream>>>(W_fc2, Wt_fc2, 3072, 768);

  ln_kernel<<<4096, 256, 0, stream>>>(x, ln1_w, ln1_b, t_ln);
  gemm_bt<0, 128><<<18 * 32, 256, 0, stream>>>(
      t_ln, Wt_attn, b_attn, nullptr, t_qkv, nullptr, 4096, 2304, 768, 18);
  attn_kernel<<<dim3(768), 256, 0, stream>>>(t_qkv, t_att);
  gemm_bt<1, 64><<<12 * 32, 256, 0, stream>>>(
      t_att, Wt_proj, b_proj, x, nullptr, t_x1, 4096, 768, 768, 12);
  ln_kernel<<<4096, 256, 0, stream>>>(t_x1, ln2_w, ln2_b, t_ln);
  gemm_bt<2, 128><<<24 * 32, 256, 0, stream>>>(
      t_ln, Wt_fc, b_fc, nullptr, t_h, nullptr, 4096, 3072, 768, 24);
  gemm_bt<1, 64><<<12 * 32, 256, 0, stream>>>(
      t_h, Wt_fc2, b_fc2, t_x1, nullptr, out, 4096, 768, 3072, 12);
}

// Round 8
// 198.523 us; speedup vs baseline: 1.1220x; 1.0330x over previous
//
#include <hip/hip_runtime.h>
#include <hip/hip_bf16.h>
#include <math.h>
#include <type_traits>

#define TSEQ 4096
#define CDIM 768
#define NH 12
#define HD 64

typedef float f32x4 __attribute__((ext_vector_type(4)));
typedef __bf16 bf16x8 __attribute__((ext_vector_type(8)));
typedef short s16x8 __attribute__((ext_vector_type(8)));
typedef uint u32x4 __attribute__((ext_vector_type(4)));

__device__ inline ushort f2bf(float f) {
  __hip_bfloat16 h = __float2bfloat16(f);
  return __builtin_bit_cast(ushort, h);
}

__device__ inline void async16(const void* g, void* l) {
  __builtin_amdgcn_global_load_lds(
      (__attribute__((address_space(1))) unsigned int*)(uintptr_t)g,
      (__attribute__((address_space(3))) unsigned int*)(uintptr_t)l, 16, 0, 0);
}

// v_exp_f32 computes 2^x; s_nop covers the TRANS->VALU hazard
__device__ inline float exp2_fast(float x) {
  float r;
  asm volatile("v_exp_f32 %0, %1\n\ts_nop 0" : "=v"(r) : "v"(x));
  return r;
}

// pack two f32 -> two bf16 in one u32 (lo = a, hi = b)
__device__ inline uint cvtpk(float a, float b) {
  uint r;
  asm volatile("v_cvt_pk_bf16_f32 %0, %1, %2" : "=v"(r) : "v"(a), "v"(b));
  return r;
}

// swizzled fragment read from a [64][64] bf16 tile with row-chunk XOR swizzle
__device__ inline bf16x8 frag_read(const ushort* base, int row, int kk, int lane) {
  const int byte = row * 128 + ((((kk * 4 + (lane >> 4)) ^ (row & 7))) << 4);
  return *(const bf16x8*)((const char*)base + byte);
}

// ---------------- weight transpose fp32 -> bf16, Wt[n][k] = W[k][n] -------
__global__ __launch_bounds__(256) void wconv_t(
    const float* __restrict__ W, ushort* __restrict__ Wt, int K, int N)
{
  __shared__ float sm[32][33];
  const int n0 = blockIdx.x * 32, k0 = blockIdx.y * 32;
  const int c = threadIdx.x & 31, r0 = threadIdx.x >> 5;
#pragma unroll
  for (int i = 0; i < 4; ++i) {
    const int r = r0 + i * 8;
    sm[r][c] = W[(size_t)(k0 + r) * N + n0 + c];
  }
  __syncthreads();
#pragma unroll
  for (int i = 0; i < 4; ++i) {
    const int r = r0 + i * 8;
    Wt[(size_t)(n0 + r) * K + k0 + c] = f2bf(sm[c][r]);
  }
}

// ---------------- layernorm fp32 -> bf16 ---------------------------------
__global__ __launch_bounds__(256) void ln_kernel(
    const float* __restrict__ x, const float* __restrict__ w,
    const float* __restrict__ b, ushort* __restrict__ out)
{
  const int row = blockIdx.x;
  const int tid = threadIdx.x;
  const float* xr = x + (size_t)row * CDIM;
  float v[3];
  float s1 = 0.f, s2 = 0.f;
#pragma unroll
  for (int i = 0; i < 3; ++i) {
    v[i] = xr[tid + i * 256];
    s1 += v[i];
    s2 += v[i] * v[i];
  }
#pragma unroll
  for (int off = 32; off >= 1; off >>= 1) {
    s1 += __shfl_xor(s1, off, 64);
    s2 += __shfl_xor(s2, off, 64);
  }
  __shared__ float red1[4], red2[4];
  if ((tid & 63) == 0) { red1[tid >> 6] = s1; red2[tid >> 6] = s2; }
  __syncthreads();
  s1 = red1[0] + red1[1] + red1[2] + red1[3];
  s2 = red2[0] + red2[1] + red2[2] + red2[3];
  const float mu = s1 * (1.f / CDIM);
  const float var = s2 * (1.f / CDIM) - mu * mu;
  const float inv = rsqrtf(var + 1e-5f);
#pragma unroll
  for (int i = 0; i < 3; ++i) {
    const int c = tid + i * 256;
    out[(size_t)row * CDIM + c] = f2bf((v[i] - mu) * inv * w[c] + b[c]);
  }
}

// ------- 128xBN bf16 MFMA GEMM, 3-stage pipeline (counted vmcnt) ---------
// EPI 0: bf16 out;  EPI 1: fp32 out = res + v;  EPI 2: bf16 out = gelu(v)
template <int EPI, int BN>
__global__ __launch_bounds__(256) void gemm_bt(
    const ushort* __restrict__ A, const ushort* __restrict__ Bt,
    const float* __restrict__ bias, const float* __restrict__ res,
    ushort* __restrict__ outb, float* __restrict__ outf,
    int M, int N, int K, int gx)
{
  constexpr int NW = BN / 32;
  __shared__ __align__(16) ushort As[3][128 * 32];
  __shared__ __align__(16) ushort Bs[3][BN * 32];
  const int tid = threadIdx.x;
  const int lane = tid & 63;
  const int wv = tid >> 6;
  const int nwg = (int)gridDim.x;
  const int bid = (int)blockIdx.x;
  const int sw = (bid & 7) * (nwg >> 3) + (bid >> 3);
  const int rowBase = (sw / gx) * 128;
  const int colBase = (sw % gx) * BN;
  const int wr = (wv >> 1) * 64;
  const int wc = (wv & 1) * (BN / 2);

  f32x4 acc[4][NW] = {};

  const int e0 = tid * 8;
  const int r0 = e0 >> 5, c0 = e0 & 31;
  const int e1 = (tid + 256) * 8;
  const int r1 = e1 >> 5, c1 = e1 & 31;

  const ushort* Ag0 = A + (size_t)(rowBase + r0) * K + c0;
  const ushort* Ag1 = A + (size_t)(rowBase + r1) * K + c1;
  const ushort* Bg0 = Bt + (size_t)(colBase + r0) * K + c0;
  const ushort* Bg1 = Bt + (size_t)(colBase + r1) * K + c1;

  auto stage = [&](int buf, int k0) {
    async16(Ag0 + k0, &As[buf][e0]);
    async16(Ag1 + k0, &As[buf][e1]);
    async16(Bg0 + k0, &Bs[buf][e0]);
    if (BN == 128) async16(Bg1 + k0, &Bs[buf][e1]);
  };

  const int nt = K / 32;
  stage(0, 0);
  stage(1, 32);
  int b0 = 0, b1 = 1, b2 = 2;
  for (int t = 0; t < nt; ++t) {
    if (t < nt - 1) {
      if (BN == 128) asm volatile("s_waitcnt vmcnt(4)" ::: "memory");
      else           asm volatile("s_waitcnt vmcnt(3)" ::: "memory");
    } else {
      asm volatile("s_waitcnt vmcnt(0)" ::: "memory");
    }
    __builtin_amdgcn_sched_barrier(0);
    __builtin_amdgcn_s_barrier();
    __builtin_amdgcn_sched_barrier(0);
    if (t + 2 < nt) stage(b2, t * 32 + 64);

    bf16x8 af[4], bfr[NW];
#pragma unroll
    for (int m = 0; m < 4; ++m)
      af[m] = *(const bf16x8*)&As[b0][(wr + m * 16 + (lane & 15)) * 32 + (lane >> 4) * 8];
#pragma unroll
    for (int n = 0; n < NW; ++n)
      bfr[n] = *(const bf16x8*)&Bs[b0][(wc + n * 16 + (lane & 15)) * 32 + (lane >> 4) * 8];
    __builtin_amdgcn_s_setprio(1);
#pragma unroll
    for (int m = 0; m < 4; ++m)
#pragma unroll
      for (int n = 0; n < NW; ++n)
        acc[m][n] = __builtin_amdgcn_mfma_f32_16x16x32_bf16(af[m], bfr[n], acc[m][n], 0, 0, 0);
    __builtin_amdgcn_s_setprio(0);
    const int tmp = b0; b0 = b1; b1 = b2; b2 = tmp;
  }

#pragma unroll
  for (int n = 0; n < NW; ++n) {
    const int gc = colBase + wc + n * 16 + (lane & 15);
    const float bv = bias[gc];
#pragma unroll
    for (int m = 0; m < 4; ++m) {
#pragma unroll
      for (int j = 0; j < 4; ++j) {
        const int gr = rowBase + wr + m * 16 + (lane >> 4) * 4 + j;
        const float v = acc[m][n][j] + bv;
        if (EPI == 0) {
          outb[(size_t)gr * N + gc] = f2bf(v);
        } else if (EPI == 1) {
          outf[(size_t)gr * N + gc] = res[(size_t)gr * N + gc] + v;
        } else {
          const float g = 0.5f * v * (1.0f + erff(v * 0.70710678118654752f));
          outb[(size_t)gr * N + gc] = f2bf(g);
        }
      }
    }
  }
}

// ---------------- causal flash attention, 64x64 tiles, hd=64 -------------
// Swapped QK^T, in-register P, sigma-permuted V^T, counted-vmcnt pipeline.
// Diag tile peeled (mask-free main loop); l via ones-column MFMA (accL).
__global__ __launch_bounds__(256) void attn_kernel(
    const ushort* __restrict__ qkv, ushort* __restrict__ att)
{
  __shared__ __align__(16) ushort Ks[2][64 * 64];
  __shared__ __align__(16) ushort Vt[2][64 * 64];   // V^T [d][sigma(key)]

  const int tid = threadIdx.x;
  const int lane = tid & 63;
  const int wv = tid >> 6;
  const int g = lane >> 4;
  const int ql = lane & 15;
  // snake remap: CU's resident blocks {p, 511-p, 512+p} -> balanced work
  const int p_ = blockIdx.x & 255, grp = blockIdx.x >> 8;
  const int item = (grp & 1) ? (grp * 256 + 255 - p_) : (grp * 256 + p_);
  const int qb = 63 - (item / 12);
  const int h = item % 12;
  const int t0 = qb * 64;
  const size_t rs = 3 * CDIM;
  const int qo = h * HD, ko = CDIM + h * HD, vo = 2 * CDIM + h * HD;

  const float cexp = 0.18033688f;            // 0.125 * log2(e)
  const float cbias = -32.0f * 0.18033688f;  // fixed max M_raw = 32

  // K staging: pre-swizzled global source -> linear LDS dest
  const int L0 = tid * 16, L1 = (tid + 256) * 16;
  const int r_0 = L0 >> 7, c_0 = ((L0 >> 4) & 7) ^ (r_0 & 7);
  const int r_1 = L1 >> 7, c_1 = ((L1 >> 4) & 7) ^ (r_1 & 7);
  const ushort* kg0 = qkv + (size_t)r_0 * rs + ko + c_0 * 8;
  const ushort* kg1 = qkv + (size_t)r_1 * rs + ko + c_1 * 8;

  // V reg staging: keys (vt, vt+1) x d in [vd, vd+8); sigma-permuted slot
  const int vt = (tid >> 3) * 2;
  const int vd = (tid & 7) * 8;
  const int slot2 = (32 * ((vt >> 4) >> 1) + 8 * ((vt >> 2) & 3) +
                     4 * ((vt >> 4) & 1) + (vt & 3)) * 2;  // byte offset in row
  const ushort* vg = qkv + (size_t)vt * rs + vo + vd;

  // Q fragments direct from global (bf16, 16B aligned)
  const ushort* qrow = qkv + (size_t)(t0 + wv * 16 + ql) * rs + qo + g * 8;
  const bf16x8 aq0 = *(const bf16x8*)(qrow);
  const bf16x8 aq1 = *(const bf16x8*)(qrow + 32);

  // prologue: vr(0), K(0) -> LDS, pack-write V^T(0)
  s16x8 vA0 = *(const s16x8*)(vg);
  s16x8 vA1 = *(const s16x8*)(vg + rs);
  async16(kg0, (char*)Ks[0] + L0);
  async16(kg1, (char*)Ks[0] + L1);
#pragma unroll
  for (int jj = 0; jj < 8; ++jj) {      // compiler waits vr(0) here
    const int d = vd + jj;
    const uint val = (uint)(ushort)vA0[jj] | ((uint)(ushort)vA1[jj] << 16);
    *(uint*)((char*)Vt[0] + d * 128 + (slot2 ^ (((d >> 1) & 7) << 4))) = val;
  }

  f32x4 accO[4] = {};
  f32x4 accL = {};
  const bf16x8 ones = __builtin_bit_cast(bf16x8,
      (u32x4){0x3F803F80u, 0x3F803F80u, 0x3F803F80u, 0x3F803F80u});
  const int swzv = (ql >> 1) & 7;

  int cur = 0;
  auto body = [&](int kb, int curb, auto diag_c) {
    constexpr bool DIAG = decltype(diag_c)::value;
    const size_t koff = (size_t)(kb + 1) * 64 * rs;

    // issue vr(kb+1) before the wait (stays in flight across this body)
    if (!DIAG) {
      vA0 = *(const s16x8*)(vg + koff);
      vA1 = *(const s16x8*)(vg + koff + rs);
      asm volatile("s_waitcnt vmcnt(2) lgkmcnt(0)" ::: "memory");
    } else {
      asm volatile("s_waitcnt vmcnt(0) lgkmcnt(0)" ::: "memory");
    }
    __builtin_amdgcn_sched_barrier(0);
    __builtin_amdgcn_s_barrier();
    __builtin_amdgcn_sched_barrier(0);

    // stage K(kb+1) post-barrier (other buffer; readers of it passed barrier)
    if (!DIAG) {
      async16(kg0 + koff, (char*)Ks[curb ^ 1] + L0);
      async16(kg1 + koff, (char*)Ks[curb ^ 1] + L1);
    }

    // QK^T swapped: D[key][q], key = 16n + 4g + j, q = wv*16 + ql
    f32x4 accS[4] = {};
    __builtin_amdgcn_s_setprio(1);
#pragma unroll
    for (int kk = 0; kk < 2; ++kk) {
      const bf16x8 a_q = kk ? aq1 : aq0;
#pragma unroll
      for (int n = 0; n < 4; ++n)
        accS[n] = __builtin_amdgcn_mfma_f32_16x16x32_bf16(
            frag_read(Ks[curb], n * 16 + ql, kk, lane), a_q, accS[n], 0, 0, 0);
    }
    __builtin_amdgcn_s_setprio(0);

    // p = 2^(s*c + cbias); mask only on (peeled) diag tile; pack in-reg
    uint pk[8];
#pragma unroll
    for (int n = 0; n < 4; ++n) {
      float pv[4];
#pragma unroll
      for (int j = 0; j < 4; ++j) {
        float s = exp2_fast(fmaf(accS[n][j], cexp, cbias));
        if (DIAG && (16 * n + 4 * g + j) > (wv * 16 + ql)) s = 0.f;
        pv[j] = s;
      }
      pk[2 * n] = cvtpk(pv[0], pv[1]);
      pk[2 * n + 1] = cvtpk(pv[2], pv[3]);
    }
    const bf16x8 pf0 = __builtin_bit_cast(bf16x8, (u32x4){pk[0], pk[1], pk[2], pk[3]});
    const bf16x8 pf1 = __builtin_bit_cast(bf16x8, (u32x4){pk[4], pk[5], pk[6], pk[7]});

    // PV: D[q][d]; A = in-reg P, B = Vt rows (d), k-dim = sigma slots.
    // accL: B = ones -> accL[j] = l[q = 4g+j] (exactly the layout needed).
    __builtin_amdgcn_s_setprio(1);
#pragma unroll
    for (int kk = 0; kk < 2; ++kk) {
      const bf16x8 a_p = kk ? pf1 : pf0;
#pragma unroll
      for (int n = 0; n < 4; ++n) {
        const int byte = (n * 16 + ql) * 128 + ((kk * 64 + g * 16) ^ (swzv << 4));
        const bf16x8 bv = *(const bf16x8*)((const char*)Vt[curb] + byte);
        accO[n] = __builtin_amdgcn_mfma_f32_16x16x32_bf16(a_p, bv, accO[n], 0, 0, 0);
      }
      accL = __builtin_amdgcn_mfma_f32_16x16x32_bf16(a_p, ones, accL, 0, 0, 0);
    }
    __builtin_amdgcn_s_setprio(0);

    // pack-write V^T(kb+1) (vr had the whole body to land; visible after
    // next barrier; all waves' reads of this buffer finished pre-barrier)
    if (!DIAG) {
#pragma unroll
      for (int jj = 0; jj < 8; ++jj) {
        const int d = vd + jj;
        const uint val = (uint)(ushort)vA0[jj] | ((uint)(ushort)vA1[jj] << 16);
        *(uint*)((char*)Vt[curb ^ 1] + d * 128 + (slot2 ^ (((d >> 1) & 7) << 4))) = val;
      }
    }
  };

  for (int kb = 0; kb < qb; ++kb) {
    body(kb, cur, std::false_type{});
    cur ^= 1;
  }
  body(qb, cur, std::true_type{});

  // accL[jr] = l for q-row 4g+jr of this wave's 16-row group
  float inv[4];
#pragma unroll
  for (int jr = 0; jr < 4; ++jr) inv[jr] = 1.0f / accL[jr];
#pragma unroll
  for (int n = 0; n < 4; ++n)
#pragma unroll
    for (int jr = 0; jr < 4; ++jr) {
      const int tq = t0 + wv * 16 + 4 * g + jr;
      const int d = n * 16 + ql;
      att[(size_t)tq * CDIM + h * HD + d] = f2bf(accO[n][jr] * inv[jr]);
    }
}

// -------------------------------------------------------------------------
extern "C" void kernel_launch(void* const* d_in, const int* in_sizes, int n_in,
                              void* d_out, int out_size, void* d_ws, size_t ws_size,
                              hipStream_t stream)
{
  const float* x      = (const float*)d_in[0];
  const float* ln1_w  = (const float*)d_in[1];
  const float* ln1_b  = (const float*)d_in[2];
  const float* W_attn = (const float*)d_in[3];
  const float* b_attn = (const float*)d_in[4];
  const float* W_proj = (const float*)d_in[5];
  const float* b_proj = (const float*)d_in[6];
  const float* ln2_w  = (const float*)d_in[7];
  const float* ln2_b  = (const float*)d_in[8];
  const float* W_fc   = (const float*)d_in[9];
  const float* b_fc   = (const float*)d_in[10];
  const float* W_fc2  = (const float*)d_in[11];
  const float* b_fc2  = (const float*)d_in[12];
  float* out = (float*)d_out;

  char* base = (char*)d_ws;
  size_t off = 0;
  auto alloc = [&](size_t bytes) -> void* {
    void* q = base + off;
    off = (off + bytes + 255) & ~(size_t)255;
    return q;
  };
  ushort* Wt_attn = (ushort*)alloc(768ull * 2304 * 2);
  ushort* Wt_proj = (ushort*)alloc(768ull * 768 * 2);
  ushort* Wt_fc   = (ushort*)alloc(768ull * 3072 * 2);
  ushort* Wt_fc2  = (ushort*)alloc(3072ull * 768 * 2);
  ushort* t_ln    = (ushort*)alloc(4096ull * 768 * 2);
  ushort* t_att   = (ushort*)alloc(4096ull * 768 * 2);
  float*  t_x1    = (float*) alloc(4096ull * 768 * 4);
  ushort* t_big   = (ushort*)alloc(4096ull * 3072 * 2);
  ushort* t_qkv = t_big;
  ushort* t_h   = t_big;

  wconv_t<<<dim3(2304 / 32, 768 / 32), 256, 0, stream>>>(W_attn, Wt_attn, 768, 2304);
  wconv_t<<<dim3(768 / 32, 768 / 32), 256, 0, stream>>>(W_proj, Wt_proj, 768, 768);
  wconv_t<<<dim3(3072 / 32, 768 / 32), 256, 0, stream>>>(W_fc, Wt_fc, 768, 3072);
  wconv_t<<<dim3(768 / 32, 3072 / 32), 256, 0, stream>>>(W_fc2, Wt_fc2, 3072, 768);

  ln_kernel<<<4096, 256, 0, stream>>>(x, ln1_w, ln1_b, t_ln);
  gemm_bt<0, 128><<<18 * 32, 256, 0, stream>>>(
      t_ln, Wt_attn, b_attn, nullptr, t_qkv, nullptr, 4096, 2304, 768, 18);
  attn_kernel<<<dim3(768), 256, 0, stream>>>(t_qkv, t_att);
  gemm_bt<1, 64><<<12 * 32, 256, 0, stream>>>(
      t_att, Wt_proj, b_proj, x, nullptr, t_x1, 4096, 768, 768, 12);
  ln_kernel<<<4096, 256, 0, stream>>>(t_x1, ln2_w, ln2_b, t_ln);
  gemm_bt<2, 128><<<24 * 32, 256, 0, stream>>>(
      t_ln, Wt_fc, b_fc, nullptr, t_h, nullptr, 4096, 3072, 768, 24);
  gemm_bt<1, 64><<<12 * 32, 256, 0, stream>>>(
      t_h, Wt_fc2, b_fc2, t_x1, nullptr, out, 4096, 768, 3072, 12);
}

// Round 9
// 194.727 us; speedup vs baseline: 1.1438x; 1.0195x over previous
//
#include <hip/hip_runtime.h>
#include <hip/hip_bf16.h>
#include <math.h>
#include <type_traits>

#define TSEQ 4096
#define CDIM 768
#define NH 12
#define HD 64

typedef float f32x4 __attribute__((ext_vector_type(4)));
typedef __bf16 bf16x8 __attribute__((ext_vector_type(8)));
typedef short s16x8 __attribute__((ext_vector_type(8)));
typedef uint u32x4 __attribute__((ext_vector_type(4)));

__device__ inline ushort f2bf(float f) {
  __hip_bfloat16 h = __float2bfloat16(f);
  return __builtin_bit_cast(ushort, h);
}

__device__ inline void async16(const void* g, void* l) {
  __builtin_amdgcn_global_load_lds(
      (__attribute__((address_space(1))) unsigned int*)(uintptr_t)g,
      (__attribute__((address_space(3))) unsigned int*)(uintptr_t)l, 16, 0, 0);
}

// v_exp_f32 computes 2^x; s_nop covers the TRANS->VALU hazard
__device__ inline float exp2_fast(float x) {
  float r;
  asm volatile("v_exp_f32 %0, %1\n\ts_nop 0" : "=v"(r) : "v"(x));
  return r;
}

// pack two f32 -> two bf16 in one u32 (lo = a, hi = b)
__device__ inline uint cvtpk(float a, float b) {
  uint r;
  asm volatile("v_cvt_pk_bf16_f32 %0, %1, %2" : "=v"(r) : "v"(a), "v"(b));
  return r;
}

// swizzled fragment read from a [64][64] bf16 tile with row-chunk XOR swizzle
__device__ inline bf16x8 frag_read(const ushort* base, int row, int kk, int lane) {
  const int byte = row * 128 + ((((kk * 4 + (lane >> 4)) ^ (row & 7))) << 4);
  return *(const bf16x8*)((const char*)base + byte);
}

// ---------------- weight transpose fp32 -> bf16, Wt[n][k] = W[k][n] -------
__global__ __launch_bounds__(256) void wconv_t(
    const float* __restrict__ W, ushort* __restrict__ Wt, int K, int N)
{
  __shared__ float sm[32][33];
  const int n0 = blockIdx.x * 32, k0 = blockIdx.y * 32;
  const int c = threadIdx.x & 31, r0 = threadIdx.x >> 5;
#pragma unroll
  for (int i = 0; i < 4; ++i) {
    const int r = r0 + i * 8;
    sm[r][c] = W[(size_t)(k0 + r) * N + n0 + c];
  }
  __syncthreads();
#pragma unroll
  for (int i = 0; i < 4; ++i) {
    const int r = r0 + i * 8;
    Wt[(size_t)(n0 + r) * K + k0 + c] = f2bf(sm[c][r]);
  }
}

// ---------------- layernorm fp32 -> bf16 ---------------------------------
__global__ __launch_bounds__(256) void ln_kernel(
    const float* __restrict__ x, const float* __restrict__ w,
    const float* __restrict__ b, ushort* __restrict__ out)
{
  const int row = blockIdx.x;
  const int tid = threadIdx.x;
  const float* xr = x + (size_t)row * CDIM;
  float v[3];
  float s1 = 0.f, s2 = 0.f;
#pragma unroll
  for (int i = 0; i < 3; ++i) {
    v[i] = xr[tid + i * 256];
    s1 += v[i];
    s2 += v[i] * v[i];
  }
#pragma unroll
  for (int off = 32; off >= 1; off >>= 1) {
    s1 += __shfl_xor(s1, off, 64);
    s2 += __shfl_xor(s2, off, 64);
  }
  __shared__ float red1[4], red2[4];
  if ((tid & 63) == 0) { red1[tid >> 6] = s1; red2[tid >> 6] = s2; }
  __syncthreads();
  s1 = red1[0] + red1[1] + red1[2] + red1[3];
  s2 = red2[0] + red2[1] + red2[2] + red2[3];
  const float mu = s1 * (1.f / CDIM);
  const float var = s2 * (1.f / CDIM) - mu * mu;
  const float inv = rsqrtf(var + 1e-5f);
#pragma unroll
  for (int i = 0; i < 3; ++i) {
    const int c = tid + i * 256;
    out[(size_t)row * CDIM + c] = f2bf((v[i] - mu) * inv * w[c] + b[c]);
  }
}

// ------- 128xBN bf16 MFMA GEMM, 3-stage pipeline (counted vmcnt) ---------
// EPI 0: bf16 out;  EPI 1: fp32 out = res + v;  EPI 2: bf16 out = gelu(v)
template <int EPI, int BN>
__global__ __launch_bounds__(256) void gemm_bt(
    const ushort* __restrict__ A, const ushort* __restrict__ Bt,
    const float* __restrict__ bias, const float* __restrict__ res,
    ushort* __restrict__ outb, float* __restrict__ outf,
    int M, int N, int K, int gx)
{
  constexpr int NW = BN / 32;
  __shared__ __align__(16) ushort As[3][128 * 32];
  __shared__ __align__(16) ushort Bs[3][BN * 32];
  const int tid = threadIdx.x;
  const int lane = tid & 63;
  const int wv = tid >> 6;
  const int nwg = (int)gridDim.x;
  const int bid = (int)blockIdx.x;
  const int sw = (bid & 7) * (nwg >> 3) + (bid >> 3);
  const int rowBase = (sw / gx) * 128;
  const int colBase = (sw % gx) * BN;
  const int wr = (wv >> 1) * 64;
  const int wc = (wv & 1) * (BN / 2);

  f32x4 acc[4][NW] = {};

  const int e0 = tid * 8;
  const int r0 = e0 >> 5, c0 = e0 & 31;
  const int e1 = (tid + 256) * 8;
  const int r1 = e1 >> 5, c1 = e1 & 31;

  const ushort* Ag0 = A + (size_t)(rowBase + r0) * K + c0;
  const ushort* Ag1 = A + (size_t)(rowBase + r1) * K + c1;
  const ushort* Bg0 = Bt + (size_t)(colBase + r0) * K + c0;
  const ushort* Bg1 = Bt + (size_t)(colBase + r1) * K + c1;

  auto stage = [&](int buf, int k0) {
    async16(Ag0 + k0, &As[buf][e0]);
    async16(Ag1 + k0, &As[buf][e1]);
    async16(Bg0 + k0, &Bs[buf][e0]);
    if (BN == 128) async16(Bg1 + k0, &Bs[buf][e1]);
  };

  const int nt = K / 32;
  stage(0, 0);
  stage(1, 32);
  int b0 = 0, b1 = 1, b2 = 2;
  for (int t = 0; t < nt; ++t) {
    if (t < nt - 1) {
      if (BN == 128) asm volatile("s_waitcnt vmcnt(4)" ::: "memory");
      else           asm volatile("s_waitcnt vmcnt(3)" ::: "memory");
    } else {
      asm volatile("s_waitcnt vmcnt(0)" ::: "memory");
    }
    __builtin_amdgcn_sched_barrier(0);
    __builtin_amdgcn_s_barrier();
    __builtin_amdgcn_sched_barrier(0);
    if (t + 2 < nt) stage(b2, t * 32 + 64);

    bf16x8 af[4], bfr[NW];
#pragma unroll
    for (int m = 0; m < 4; ++m)
      af[m] = *(const bf16x8*)&As[b0][(wr + m * 16 + (lane & 15)) * 32 + (lane >> 4) * 8];
#pragma unroll
    for (int n = 0; n < NW; ++n)
      bfr[n] = *(const bf16x8*)&Bs[b0][(wc + n * 16 + (lane & 15)) * 32 + (lane >> 4) * 8];
    __builtin_amdgcn_s_setprio(1);
#pragma unroll
    for (int m = 0; m < 4; ++m)
#pragma unroll
      for (int n = 0; n < NW; ++n)
        acc[m][n] = __builtin_amdgcn_mfma_f32_16x16x32_bf16(af[m], bfr[n], acc[m][n], 0, 0, 0);
    __builtin_amdgcn_s_setprio(0);
    const int tmp = b0; b0 = b1; b1 = b2; b2 = tmp;
  }

#pragma unroll
  for (int n = 0; n < NW; ++n) {
    const int gc = colBase + wc + n * 16 + (lane & 15);
    const float bv = bias[gc];
#pragma unroll
    for (int m = 0; m < 4; ++m) {
#pragma unroll
      for (int j = 0; j < 4; ++j) {
        const int gr = rowBase + wr + m * 16 + (lane >> 4) * 4 + j;
        const float v = acc[m][n][j] + bv;
        if (EPI == 0) {
          outb[(size_t)gr * N + gc] = f2bf(v);
        } else if (EPI == 1) {
          outf[(size_t)gr * N + gc] = res[(size_t)gr * N + gc] + v;
        } else {
          const float g = 0.5f * v * (1.0f + erff(v * 0.70710678118654752f));
          outb[(size_t)gr * N + gc] = f2bf(g);
        }
      }
    }
  }
}

// ---------------- causal flash attention, 64x64 tiles, hd=64 -------------
// 2D wave split: wave (kh=wv&1, qh=wv>>1) owns keys [32kh,32kh+32) x
// q rows [32qh,32qh+32). Halves per-wave LDS reads (4+4 b128/tile).
// Fixed-max softmax => key-partials additive; one merge at end (kh pair).
// sigma(key-in-slice)=8g+4kg+j permutation on V^T columns makes the packed
// softmax registers directly the PV A-fragment (round-4-verified scheme).
__global__ __launch_bounds__(256) void attn_kernel(
    const ushort* __restrict__ qkv, ushort* __restrict__ att)
{
  __shared__ __align__(16) ushort Ks[2][64 * 64];
  __shared__ __align__(16) ushort Vt[2][64 * 64];   // V^T [d][col: kh*32+sigma]

  const int tid = threadIdx.x;
  const int lane = tid & 63;
  const int wv = tid >> 6;
  const int g = lane >> 4;
  const int ql = lane & 15;
  const int kh = wv & 1;          // key-half owned
  const int qh = wv >> 1;         // q-half owned
  // snake remap: CU's resident blocks {p, 511-p, 512+p} -> balanced work
  const int p_ = blockIdx.x & 255, grp = blockIdx.x >> 8;
  const int item = (grp & 1) ? (grp * 256 + 255 - p_) : (grp * 256 + p_);
  const int qb = 63 - (item / 12);
  const int h = item % 12;
  const int t0 = qb * 64;
  const size_t rs = 3 * CDIM;
  const int qo = h * HD, ko = CDIM + h * HD, vo = 2 * CDIM + h * HD;

  const float cexp = 0.18033688f;            // 0.125 * log2(e)
  const float cbias = -32.0f * 0.18033688f;  // fixed max M_raw = 32

  // K staging: pre-swizzled global source -> linear LDS dest
  const int L0 = tid * 16, L1 = (tid + 256) * 16;
  const int r_0 = L0 >> 7, c_0 = ((L0 >> 4) & 7) ^ (r_0 & 7);
  const int r_1 = L1 >> 7, c_1 = ((L1 >> 4) & 7) ^ (r_1 & 7);
  const ushort* kg0 = qkv + (size_t)r_0 * rs + ko + c_0 * 8;
  const ushort* kg1 = qkv + (size_t)r_1 * rs + ko + c_1 * 8;

  // V reg staging: keys (vt, vt+1) x d in [vd, vd+8)
  // column: kh_w*64B + 2*sigma(s32), sigma = 8*((s32>>2)&3) + 4*(s32>>4) + (s32&3)
  const int vt = (tid >> 3) * 2;
  const int vd = (tid & 7) * 8;
  const int s32 = vt & 31;
  const int col2 = (vt >> 5) * 64 + (8 * ((s32 >> 2) & 3) + 4 * (s32 >> 4) + (s32 & 3)) * 2;
  const ushort* vg = qkv + (size_t)vt * rs + vo + vd;

  // Q fragments: q rows 32qh + 16qg + ql, d-chunks kk
  bf16x8 qf[2][2];
#pragma unroll
  for (int qg = 0; qg < 2; ++qg) {
    const ushort* qrow = qkv + (size_t)(t0 + 32 * qh + 16 * qg + ql) * rs + qo + g * 8;
    qf[qg][0] = *(const bf16x8*)(qrow);
    qf[qg][1] = *(const bf16x8*)(qrow + 32);
  }

  // prologue: vr(0), K(0) -> LDS, pack-write V^T(0)
  s16x8 vA0 = *(const s16x8*)(vg);
  s16x8 vA1 = *(const s16x8*)(vg + rs);
  async16(kg0, (char*)Ks[0] + L0);
  async16(kg1, (char*)Ks[0] + L1);
#pragma unroll
  for (int jj = 0; jj < 8; ++jj) {      // compiler waits vr(0) here
    const int d = vd + jj;
    const uint val = (uint)(ushort)vA0[jj] | ((uint)(ushort)vA1[jj] << 16);
    *(uint*)((char*)Vt[0] + d * 128 + (col2 ^ (((d >> 1) & 7) << 4))) = val;
  }

  f32x4 accO[2][4] = {};
  f32x4 accL[2] = {};
  const bf16x8 ones = __builtin_bit_cast(bf16x8,
      (u32x4){0x3F803F80u, 0x3F803F80u, 0x3F803F80u, 0x3F803F80u});
  const int swzv = (ql >> 1) & 7;

  int cur = 0;
  auto body = [&](int kb, int curb, auto diag_c) {
    constexpr bool DIAG = decltype(diag_c)::value;
    const size_t koff = (size_t)(kb + 1) * 64 * rs;

    // issue vr(kb+1) before the wait (stays in flight across this body)
    if (!DIAG) {
      vA0 = *(const s16x8*)(vg + koff);
      vA1 = *(const s16x8*)(vg + koff + rs);
      asm volatile("s_waitcnt vmcnt(2) lgkmcnt(0)" ::: "memory");
    } else {
      asm volatile("s_waitcnt vmcnt(0) lgkmcnt(0)" ::: "memory");
    }
    __builtin_amdgcn_sched_barrier(0);
    __builtin_amdgcn_s_barrier();
    __builtin_amdgcn_sched_barrier(0);

    // stage K(kb+1) post-barrier (other buffer; readers of it passed barrier)
    if (!DIAG) {
      async16(kg0 + koff, (char*)Ks[curb ^ 1] + L0);
      async16(kg1 + koff, (char*)Ks[curb ^ 1] + L1);
    }

    // QK^T: D[key][q]; A = K rows (wave's 32), B = Q (wave's 32 rows, regs)
    f32x4 accS[2][2] = {};   // [kg][qg]
    __builtin_amdgcn_s_setprio(1);
#pragma unroll
    for (int kg = 0; kg < 2; ++kg)
#pragma unroll
      for (int kk = 0; kk < 2; ++kk) {
        const bf16x8 A = frag_read(Ks[curb], 32 * kh + 16 * kg + ql, kk, lane);
#pragma unroll
        for (int qg = 0; qg < 2; ++qg)
          accS[kg][qg] = __builtin_amdgcn_mfma_f32_16x16x32_bf16(
              A, qf[qg][kk], accS[kg][qg], 0, 0, 0);
      }
    __builtin_amdgcn_s_setprio(0);

    // p = 2^(s*c + cbias); mask only on peeled diag tile; pack in-reg
    // lane holds P[key=32kh+16kg+4g+j][q=32qh+16qg+ql]; sigma slot = 8g+4kg+j
    bf16x8 pa[2];
#pragma unroll
    for (int qg = 0; qg < 2; ++qg) {
      float e[2][4];
#pragma unroll
      for (int kg = 0; kg < 2; ++kg)
#pragma unroll
        for (int j = 0; j < 4; ++j) {
          float s = exp2_fast(fmaf(accS[kg][qg][j], cexp, cbias));
          if (DIAG && (32 * kh + 16 * kg + 4 * g + j) > (32 * qh + 16 * qg + ql)) s = 0.f;
          e[kg][j] = s;
        }
      const uint w0 = cvtpk(e[0][0], e[0][1]);
      const uint w1 = cvtpk(e[0][2], e[0][3]);
      const uint w2 = cvtpk(e[1][0], e[1][1]);
      const uint w3 = cvtpk(e[1][2], e[1][3]);
      pa[qg] = __builtin_bit_cast(bf16x8, (u32x4){w0, w1, w2, w3});
    }

    // PV: D[q][d]; A = pa (k = wave's 32 sigma slots), B = Vt rows (d),
    // reading only the wave's 32-key column slice. accL: B = ones.
    __builtin_amdgcn_s_setprio(1);
#pragma unroll
    for (int n = 0; n < 4; ++n) {
      const int byte = (16 * n + ql) * 128 + ((kh * 64 + 16 * g) ^ (swzv << 4));
      const bf16x8 bv = *(const bf16x8*)((const char*)Vt[curb] + byte);
#pragma unroll
      for (int qg = 0; qg < 2; ++qg)
        accO[qg][n] = __builtin_amdgcn_mfma_f32_16x16x32_bf16(pa[qg], bv, accO[qg][n], 0, 0, 0);
    }
#pragma unroll
    for (int qg = 0; qg < 2; ++qg)
      accL[qg] = __builtin_amdgcn_mfma_f32_16x16x32_bf16(pa[qg], ones, accL[qg], 0, 0, 0);
    __builtin_amdgcn_s_setprio(0);

    // pack-write V^T(kb+1) (vr had the whole body to land; visible after
    // next barrier; all waves' reads of this buffer finished pre-barrier)
    if (!DIAG) {
#pragma unroll
      for (int jj = 0; jj < 8; ++jj) {
        const int d = vd + jj;
        const uint val = (uint)(ushort)vA0[jj] | ((uint)(ushort)vA1[jj] << 16);
        *(uint*)((char*)Vt[curb ^ 1] + d * 128 + (col2 ^ (((d >> 1) & 7) << 4))) = val;
      }
    }
  };

  for (int kb = 0; kb < qb; ++kb) {
    body(kb, cur, std::false_type{});
    cur ^= 1;
  }
  body(qb, cur, std::true_type{});

  // -------- merge kh partials (fixed-max => exactly additive) ------------
  __syncthreads();                       // all PV reads of Vt/Ks done
  float* mO = (float*)&Ks[0][0];         // [qh][qg][n][lane] f32x4 = 16KB
  float* mL = (float*)&Vt[0][0];         // [qh][qg][lane] f32x4 = 4KB
  if (kh == 1) {
#pragma unroll
    for (int qg = 0; qg < 2; ++qg) {
#pragma unroll
      for (int n = 0; n < 4; ++n)
        *(f32x4*)&mO[(((qh * 2 + qg) * 4 + n) * 64 + lane) * 4] = accO[qg][n];
      *(f32x4*)&mL[((qh * 2 + qg) * 64 + lane) * 4] = accL[qg];
    }
  }
  __syncthreads();
  if (kh == 0) {
#pragma unroll
    for (int qg = 0; qg < 2; ++qg) {
      const f32x4 ls = accL[qg] + *(const f32x4*)&mL[((qh * 2 + qg) * 64 + lane) * 4];
      f32x4 inv4;
#pragma unroll
      for (int jr = 0; jr < 4; ++jr) inv4[jr] = 1.0f / ls[jr];
#pragma unroll
      for (int n = 0; n < 4; ++n) {
        const f32x4 o = accO[qg][n] +
            *(const f32x4*)&mO[(((qh * 2 + qg) * 4 + n) * 64 + lane) * 4];
#pragma unroll
        for (int jr = 0; jr < 4; ++jr) {
          const int tq = t0 + 32 * qh + 16 * qg + 4 * g + jr;
          const int d = 16 * n + ql;
          att[(size_t)tq * CDIM + h * HD + d] = f2bf(o[jr] * inv4[jr]);
        }
      }
    }
  }
}

// -------------------------------------------------------------------------
extern "C" void kernel_launch(void* const* d_in, const int* in_sizes, int n_in,
                              void* d_out, int out_size, void* d_ws, size_t ws_size,
                              hipStream_t stream)
{
  const float* x      = (const float*)d_in[0];
  const float* ln1_w  = (const float*)d_in[1];
  const float* ln1_b  = (const float*)d_in[2];
  const float* W_attn = (const float*)d_in[3];
  const float* b_attn = (const float*)d_in[4];
  const float* W_proj = (const float*)d_in[5];
  const float* b_proj = (const float*)d_in[6];
  const float* ln2_w  = (const float*)d_in[7];
  const float* ln2_b  = (const float*)d_in[8];
  const float* W_fc   = (const float*)d_in[9];
  const float* b_fc   = (const float*)d_in[10];
  const float* W_fc2  = (const float*)d_in[11];
  const float* b_fc2  = (const float*)d_in[12];
  float* out = (float*)d_out;

  char* base = (char*)d_ws;
  size_t off = 0;
  auto alloc = [&](size_t bytes) -> void* {
    void* q = base + off;
    off = (off + bytes + 255) & ~(size_t)255;
    return q;
  };
  ushort* Wt_attn = (ushort*)alloc(768ull * 2304 * 2);
  ushort* Wt_proj = (ushort*)alloc(768ull * 768 * 2);
  ushort* Wt_fc   = (ushort*)alloc(768ull * 3072 * 2);
  ushort* Wt_fc2  = (ushort*)alloc(3072ull * 768 * 2);
  ushort* t_ln    = (ushort*)alloc(4096ull * 768 * 2);
  ushort* t_att   = (ushort*)alloc(4096ull * 768 * 2);
  float*  t_x1    = (float*) alloc(4096ull * 768 * 4);
  ushort* t_big   = (ushort*)alloc(4096ull * 3072 * 2);
  ushort* t_qkv = t_big;
  ushort* t_h   = t_big;

  wconv_t<<<dim3(2304 / 32, 768 / 32), 256, 0, stream>>>(W_attn, Wt_attn, 768, 2304);
  wconv_t<<<dim3(768 / 32, 768 / 32), 256, 0, stream>>>(W_proj, Wt_proj, 768, 768);
  wconv_t<<<dim3(3072 / 32, 768 / 32), 256, 0, stream>>>(W_fc, Wt_fc, 768, 3072);
  wconv_t<<<dim3(768 / 32, 3072 / 32), 256, 0, stream>>>(W_fc2, Wt_fc2, 3072, 768);

  ln_kernel<<<4096, 256, 0, stream>>>(x, ln1_w, ln1_b, t_ln);
  gemm_bt<0, 128><<<18 * 32, 256, 0, stream>>>(
      t_ln, Wt_attn, b_attn, nullptr, t_qkv, nullptr, 4096, 2304, 768, 18);
  attn_kernel<<<dim3(768), 256, 0, stream>>>(t_qkv, t_att);
  gemm_bt<1, 64><<<12 * 32, 256, 0, stream>>>(
      t_att, Wt_proj, b_proj, x, nullptr, t_x1, 4096, 768, 768, 12);
  ln_kernel<<<4096, 256, 0, stream>>>(t_x1, ln2_w, ln2_b, t_ln);
  gemm_bt<2, 128><<<24 * 32, 256, 0, stream>>>(
      t_ln, Wt_fc, b_fc, nullptr, t_h, nullptr, 4096, 3072, 768, 24);
  gemm_bt<1, 64><<<12 * 32, 256, 0, stream>>>(
      t_h, Wt_fc2, b_fc2, t_x1, nullptr, out, 4096, 768, 3072, 12);
}